// Round 1
// baseline (129.963 us; speedup 1.0000x reference)
//
#include <hip/hip_runtime.h>
#include <stdint.h>

#define NN 8192
#define KD 512
#define BM 128
#define BN 128
#define BK 32

typedef __bf16 bf16;
typedef __bf16 bf16x8 __attribute__((ext_vector_type(8)));
typedef float f32x4 __attribute__((ext_vector_type(4)));

// ---------------- kernel 1: row L2-normalize, fp32 -> bf16 ----------------
// one wave per row; 8 floats/lane (2x float4); 64-lane shuffle reduce
__global__ __launch_bounds__(256) void rownorm_kernel(const float* __restrict__ proto,
                                                      bf16* __restrict__ pn) {
    const int row  = blockIdx.x * 4 + (threadIdx.x >> 6);
    const int lane = threadIdx.x & 63;
    const float4* src = (const float4*)(proto + (size_t)row * KD) + lane * 2;
    const float4 v0 = src[0];
    const float4 v1 = src[1];
    float s = v0.x*v0.x + v0.y*v0.y + v0.z*v0.z + v0.w*v0.w
            + v1.x*v1.x + v1.y*v1.y + v1.z*v1.z + v1.w*v1.w;
#pragma unroll
    for (int off = 32; off; off >>= 1) s += __shfl_xor(s, off);
    const float inv = 1.0f / fmaxf(sqrtf(s), 1e-12f);   // matches max(norm, EPS)
    bf16x8 o;
    o[0] = (bf16)(v0.x*inv); o[1] = (bf16)(v0.y*inv);
    o[2] = (bf16)(v0.z*inv); o[3] = (bf16)(v0.w*inv);
    o[4] = (bf16)(v1.x*inv); o[5] = (bf16)(v1.y*inv);
    o[6] = (bf16)(v1.z*inv); o[7] = (bf16)(v1.w*inv);
    *(bf16x8*)(pn + (size_t)row * KD + lane * 8) = o;
}

// ---------------- kernel 2: C = leakyrelu(P P^T), bf16 MFMA ----------------
__device__ __forceinline__ void gload_lds16(const bf16* g, bf16* l) {
    __builtin_amdgcn_global_load_lds(
        (const __attribute__((address_space(1))) void*)g,
        (__attribute__((address_space(3))) void*)l, 16, 0, 0);
}

__global__ __launch_bounds__(256) void gemm_sym_kernel(const bf16* __restrict__ P,
                                                       float* __restrict__ C) {
    __shared__ bf16 sA[BM][BK];
    __shared__ bf16 sB[BN][BK];

    // bijective XCD swizzle: 4096 blocks, 8 XCDs, 512 contiguous tiles per XCD
    const int bid = blockIdx.x;
    const int swz = (bid & 7) * 512 + (bid >> 3);
    const int tm = swz >> 6;     // 64 tiles per row
    const int tn = swz & 63;

    const int tid  = threadIdx.x;
    const int w    = tid >> 6;         // wave 0..3 (2x2)
    const int lane = tid & 63;
    const int rowA0 = tm * BM;
    const int rowB0 = tn * BN;
    const int wm = (w >> 1) * 64;
    const int wn = (w & 1) * 64;
    const int rsel  = lane & 15;       // A/B fragment row/col
    const int khalf = (lane >> 4) * 8; // k sub-offset within BK=32

    f32x4 acc[4][4] = {};

    for (int kt = 0; kt < KD; kt += BK) {
        if (kt) __syncthreads();
        // stage A,B tiles: per wave 2 slots x 1024B; LDS dest = uniform base + lane*16
#pragma unroll
        for (int s = 0; s < 2; ++s) {
            const int chunk = (w * 2 + s) * 64 + lane;   // 0..511 (16B chunks)
            const int r  = chunk >> 2;                   // row 0..127
            const int ce = (chunk & 3) * 8;              // col element 0/8/16/24
            gload_lds16(P + (size_t)(rowA0 + r) * KD + kt + ce,
                        &sA[0][0] + (w * 2 + s) * 512);
            gload_lds16(P + (size_t)(rowB0 + r) * KD + kt + ce,
                        &sB[0][0] + (w * 2 + s) * 512);
        }
        __syncthreads();   // compiler emits vmcnt(0) drain before barrier

        bf16x8 af[4], bfr[4];
#pragma unroll
        for (int m = 0; m < 4; ++m)
            af[m] = *(const bf16x8*)&sA[wm + m * 16 + rsel][khalf];
#pragma unroll
        for (int n = 0; n < 4; ++n)
            bfr[n] = *(const bf16x8*)&sB[wn + n * 16 + rsel][khalf];
#pragma unroll
        for (int m = 0; m < 4; ++m)
#pragma unroll
            for (int n = 0; n < 4; ++n)
                acc[m][n] = __builtin_amdgcn_mfma_f32_16x16x32_bf16(
                    af[m], bfr[n], acc[m][n], 0, 0, 0);
    }

    // epilogue: leaky-relu + scalar stores (16-lane x 64B coalesced segments)
    const int cr = (lane >> 4) * 4;
    const int cc = lane & 15;
#pragma unroll
    for (int m = 0; m < 4; ++m)
#pragma unroll
        for (int n = 0; n < 4; ++n)
#pragma unroll
            for (int r = 0; r < 4; ++r) {
                float v = acc[m][n][r];
                v = (v >= 0.0f) ? v : 0.01f * v;
                C[(size_t)(rowA0 + wm + m * 16 + cr + r) * NN
                  + (rowB0 + wn + n * 16 + cc)] = v;
            }
}

extern "C" void kernel_launch(void* const* d_in, const int* in_sizes, int n_in,
                              void* d_out, int out_size, void* d_ws, size_t ws_size,
                              hipStream_t stream) {
    // inputs: d_in[0] = x (unused by reference), d_in[1] = proto (8192x512 fp32)
    const float* proto = (const float*)d_in[1];
    float* C  = (float*)d_out;
    bf16* pn  = (bf16*)d_ws;   // 8192*512*2 = 8 MB scratch

    rownorm_kernel<<<dim3(NN / 4), dim3(256), 0, stream>>>(proto, pn);
    gemm_sym_kernel<<<dim3((NN / BM) * (NN / BN)), dim3(256), 0, stream>>>(pn, C);
}

// Round 2
// 99.290 us; speedup vs baseline: 1.3089x; 1.3089x over previous
//
#include <hip/hip_runtime.h>
#include <stdint.h>

#define NN 8192
#define KD 512
#define BM 128
#define BN 128
#define BK 32
#define NTILE (NN / BM)            // 64
#define NTRI (NTILE * (NTILE + 1) / 2)  // 2080

typedef __bf16 bf16;
typedef __bf16 bf16x8 __attribute__((ext_vector_type(8)));
typedef float f32x4 __attribute__((ext_vector_type(4)));

// ---------------- kernel 1: row L2-normalize, fp32 -> bf16 ----------------
__global__ __launch_bounds__(256) void rownorm_kernel(const float* __restrict__ proto,
                                                      bf16* __restrict__ pn) {
    const int row  = blockIdx.x * 4 + (threadIdx.x >> 6);
    const int lane = threadIdx.x & 63;
    const float4* src = (const float4*)(proto + (size_t)row * KD) + lane * 2;
    const float4 v0 = src[0];
    const float4 v1 = src[1];
    float s = v0.x*v0.x + v0.y*v0.y + v0.z*v0.z + v0.w*v0.w
            + v1.x*v1.x + v1.y*v1.y + v1.z*v1.z + v1.w*v1.w;
#pragma unroll
    for (int off = 32; off; off >>= 1) s += __shfl_xor(s, off);
    const float inv = 1.0f / fmaxf(sqrtf(s), 1e-12f);
    bf16x8 o;
    o[0] = (bf16)(v0.x*inv); o[1] = (bf16)(v0.y*inv);
    o[2] = (bf16)(v0.z*inv); o[3] = (bf16)(v0.w*inv);
    o[4] = (bf16)(v1.x*inv); o[5] = (bf16)(v1.y*inv);
    o[6] = (bf16)(v1.z*inv); o[7] = (bf16)(v1.w*inv);
    *(bf16x8*)(pn + (size_t)row * KD + lane * 8) = o;
}

// ------- kernel 2: C = leakyrelu(P P^T), symmetric: upper-tri tiles -------
__device__ __forceinline__ void gload_lds16(const bf16* g, bf16* l) {
    __builtin_amdgcn_global_load_lds(
        (const __attribute__((address_space(1))) void*)g,
        (__attribute__((address_space(3))) void*)l, 16, 0, 0);
}

__device__ __forceinline__ float lrelu(float v) {
    return (v >= 0.0f) ? v : 0.01f * v;
}

__global__ __launch_bounds__(256) void gemm_sym_kernel(const bf16* __restrict__ P,
                                                       float* __restrict__ C) {
    __shared__ bf16 sA[BM][BK];
    __shared__ bf16 sB[BN][BK];

    // bijective XCD swizzle: 2080 blocks = 8 XCDs x 260 contiguous tiles
    const int bid = blockIdx.x;
    const int swz = (bid & 7) * (NTRI / 8) + (bid >> 3);

    // exact triangular decode: row-major over (tm, tn) with tn >= tm
    int tm = 0, rem = swz;
    while (rem >= NTILE - tm) { rem -= NTILE - tm; ++tm; }
    const int tn = tm + rem;

    const int tid  = threadIdx.x;
    const int w    = tid >> 6;         // wave 0..3 (2x2)
    const int lane = tid & 63;
    const int rowA0 = tm * BM;
    const int rowB0 = tn * BN;
    const int wm = (w >> 1) * 64;
    const int wn = (w & 1) * 64;
    const int rsel  = lane & 15;
    const int khalf = (lane >> 4) * 8;

    f32x4 acc[4][4] = {};

    for (int kt = 0; kt < KD; kt += BK) {
        if (kt) __syncthreads();
#pragma unroll
        for (int s = 0; s < 2; ++s) {
            const int chunk = (w * 2 + s) * 64 + lane;   // 0..511 (16B chunks)
            const int r  = chunk >> 2;                   // row 0..127
            const int ce = (chunk & 3) * 8;              // col 0/8/16/24
            gload_lds16(P + (size_t)(rowA0 + r) * KD + kt + ce,
                        &sA[0][0] + (w * 2 + s) * 512);
            gload_lds16(P + (size_t)(rowB0 + r) * KD + kt + ce,
                        &sB[0][0] + (w * 2 + s) * 512);
        }
        __syncthreads();

        bf16x8 af[4], bfr[4];
#pragma unroll
        for (int m = 0; m < 4; ++m)
            af[m] = *(const bf16x8*)&sA[wm + m * 16 + rsel][khalf];
#pragma unroll
        for (int n = 0; n < 4; ++n)
            bfr[n] = *(const bf16x8*)&sB[wn + n * 16 + rsel][khalf];
#pragma unroll
        for (int m = 0; m < 4; ++m)
#pragma unroll
            for (int n = 0; n < 4; ++n)
                acc[m][n] = __builtin_amdgcn_mfma_f32_16x16x32_bf16(
                    af[m], bfr[n], acc[m][n], 0, 0, 0);
    }

    const int cr = (lane >> 4) * 4;   // acc reg r -> row cr+r
    const int cc = lane & 15;         // col

    // direct tile: C[rowA0 + ...][rowB0 + ...], 16-lane x 64B segments
#pragma unroll
    for (int m = 0; m < 4; ++m)
#pragma unroll
        for (int n = 0; n < 4; ++n)
#pragma unroll
            for (int r = 0; r < 4; ++r)
                C[(size_t)(rowA0 + wm + m * 16 + cr + r) * NN
                  + (rowB0 + wn + n * 16 + cc)] = lrelu(acc[m][n][r]);

    // mirror tile (off-diagonal only): C[rowB0 + ...][rowA0 + ...]
    // per-lane float4: acc regs r=0..3 are 4 consecutive COLUMNS of C^T
    if (tm != tn) {
#pragma unroll
        for (int m = 0; m < 4; ++m)
#pragma unroll
            for (int n = 0; n < 4; ++n) {
                float4 vv;
                vv.x = lrelu(acc[m][n][0]);
                vv.y = lrelu(acc[m][n][1]);
                vv.z = lrelu(acc[m][n][2]);
                vv.w = lrelu(acc[m][n][3]);
                *(float4*)&C[(size_t)(rowB0 + wn + n * 16 + cc) * NN
                             + (rowA0 + wm + m * 16 + cr)] = vv;
            }
    }
}

extern "C" void kernel_launch(void* const* d_in, const int* in_sizes, int n_in,
                              void* d_out, int out_size, void* d_ws, size_t ws_size,
                              hipStream_t stream) {
    const float* proto = (const float*)d_in[1];
    float* C  = (float*)d_out;
    bf16* pn  = (bf16*)d_ws;   // 8 MB scratch

    rownorm_kernel<<<dim3(NN / 4), dim3(256), 0, stream>>>(proto, pn);
    gemm_sym_kernel<<<dim3(NTRI), dim3(256), 0, stream>>>(pn, C);
}